// Round 6
// baseline (627.250 us; speedup 1.0000x reference)
//
#include <hip/hip_runtime.h>
#include <math.h>

#define TT 256
#define NI 29
#define HH 128
#define NC 29
#define ROWS 16
#define PSTR 136   // fp16 plane stride (halfs); rows 272 B, 16 B-aligned

typedef _Float16 f16x8 __attribute__((ext_vector_type(8)));
typedef _Float16 f16x4 __attribute__((ext_vector_type(4)));
typedef float f32x4 __attribute__((ext_vector_type(4)));

// tanh(x) = 1 - 2/(e^{2x}+1); e^{2x} = 2^{2x*log2(e)}. Graceful at +-inf.
__device__ __forceinline__ float fast_tanh(float x) {
    float e = __builtin_amdgcn_exp2f(x * 2.885390081777927f);
    return 1.0f - 2.0f * __builtin_amdgcn_rcpf(e + 1.0f);
}

__device__ __forceinline__ f16x8 cvt8(const float4& a, const float4& b) {
    f16x8 r;
    r[0] = (_Float16)a.x; r[1] = (_Float16)a.y;
    r[2] = (_Float16)a.z; r[3] = (_Float16)a.w;
    r[4] = (_Float16)b.x; r[5] = (_Float16)b.y;
    r[6] = (_Float16)b.z; r[7] = (_Float16)b.w;
    return r;
}

// per-lane chunk of x~ = [x(29), 1(bias slot), 0, 0]: i = 8g..8g+7
__device__ __forceinline__ void load_xe(const float* p, int g, float4& a, float4& b) {
    a = *(const float4*)p;
    if (g < 3) {
        b = *(const float4*)(p + 4);
    } else {
        b.x = p[4];            // i = 28
        b.y = 1.0f;            // i = 29: constant-1 -> bias column
        b.z = 0.f; b.w = 0.f;
    }
}

#define MFMA16(A, B, C) __builtin_amdgcn_mfma_f32_16x16x32_f16((A), (B), (C), 0, 0, 0)

// W~ih[j][k]: k<29 -> Wih, k=29 -> bih+bhh (bias column), else 0
__device__ __forceinline__ void load_rnn_weights(
    const float* __restrict__ Wih, const float* __restrict__ Whh,
    const float* __restrict__ bih, const float* __restrict__ bhh,
    int m, int g, f16x8 (&Aw)[8][4], f16x8 (&AX)[8])
{
#pragma unroll
    for (int jt = 0; jt < 8; ++jt) {
        const int j = 16 * jt + m;
#pragma unroll
        for (int s = 0; s < 4; ++s) {
            const float* p = Whh + j * HH + 32 * s + 8 * g;
            float4 v0 = *(const float4*)p;
            float4 v1 = *(const float4*)(p + 4);
            Aw[jt][s] = cvt8(v0, v1);
        }
        f16x8 a;
#pragma unroll
        for (int e = 0; e < 8; ++e) {
            int k = 8 * g + e;
            float v = (k < NI) ? Wih[j * NI + k]
                               : (k == NI ? bih[j] + bhh[j] : 0.f);
            a[e] = (_Float16)v;
        }
        AX[jt] = a;
    }
}

__device__ __forceinline__ void load_fc(
    const float* __restrict__ fcW, const float* __restrict__ fcb,
    int m, int g, f16x8 (&Afc)[2][4], float (&fcbv)[2][4])
{
#pragma unroll
    for (int ct = 0; ct < 2; ++ct) {
        const int c = 16 * ct + m;
#pragma unroll
        for (int s = 0; s < 4; ++s) {
            f16x8 a;
#pragma unroll
            for (int e = 0; e < 8; ++e) {
                int k = 32 * s + 8 * g + e;
                a[e] = (c < NC) ? (_Float16)fcW[c * HH + k] : (_Float16)0.f;
            }
            Afc[ct][s] = a;
        }
#pragma unroll
        for (int q = 0; q < 4; ++q) {
            int c2 = 16 * ct + 4 * g + q;
            fcbv[ct][q] = (c2 < NC) ? fcb[c2] : 0.f;
        }
    }
}

// One recurrence step. Same-wave LDS only: reads planes[CUR], writes
// planes[CUR^1]; compiler-ordered via lgkmcnt (no barrier anywhere).
// MFMA 16x16x32 layouts (m89/m91; confirmed end-to-end R2/R4/R5):
//   A[m][k]: m=lane&15, k=(lane>>4)*8+e ; B[k][n]: n=lane&15, same k
//   C/D: col=lane&15 (batch), row=(lane>>4)*4+reg (j within tile)
#define PHASE_STEP(CUR, XF0, XF1, TV)                                         \
  {                                                                           \
    f16x8 Bh0 = *(const f16x8*)&planes[CUR][m][ 0 + 8 * g];                   \
    f16x8 Bh1 = *(const f16x8*)&planes[CUR][m][32 + 8 * g];                   \
    f16x8 Bh2 = *(const f16x8*)&planes[CUR][m][64 + 8 * g];                   \
    f16x8 Bh3 = *(const f16x8*)&planes[CUR][m][96 + 8 * g];                   \
    f16x8 BX = cvt8(XF0, XF1);                                                \
    if ((TV) + 2 < TT) load_xe(xrow + ((TV) + 2) * NI, g, XF0, XF1);          \
    f32x4 ac[8];                                                              \
    _Pragma("unroll") for (int jt = 0; jt < 8; ++jt)                          \
      ac[jt] = MFMA16(AX[jt], BX, zc);                                        \
    _Pragma("unroll") for (int jt = 0; jt < 8; ++jt)                          \
      ac[jt] = MFMA16(Aw[jt][0], Bh0, ac[jt]);                                \
    _Pragma("unroll") for (int jt = 0; jt < 8; ++jt)                          \
      ac[jt] = MFMA16(Aw[jt][1], Bh1, ac[jt]);                                \
    _Pragma("unroll") for (int jt = 0; jt < 8; ++jt)                          \
      ac[jt] = MFMA16(Aw[jt][2], Bh2, ac[jt]);                                \
    _Pragma("unroll") for (int jt = 0; jt < 8; ++jt)                          \
      ac[jt] = MFMA16(Aw[jt][3], Bh3, ac[jt]);                                \
    if (DEC && (TV) > 0) {                                                    \
      f32x4 f0 = zc, f1 = zc;                                                 \
      f0 = MFMA16(Afc[0][0], Bh0, f0);  f1 = MFMA16(Afc[1][0], Bh0, f1);      \
      f0 = MFMA16(Afc[0][1], Bh1, f0);  f1 = MFMA16(Afc[1][1], Bh1, f1);      \
      f0 = MFMA16(Afc[0][2], Bh2, f0);  f1 = MFMA16(Afc[1][2], Bh2, f1);      \
      f0 = MFMA16(Afc[0][3], Bh3, f0);  f1 = MFMA16(Afc[1][3], Bh3, f1);      \
      float* op = fcout + (long)((TV) - 1) * NC;                              \
      _Pragma("unroll") for (int q = 0; q < 4; ++q) {                         \
        op[q] = f0[q] + fcbv[0][q];                                           \
        if (16 + 4 * g + q < NC) op[16 + q] = f1[q] + fcbv[1][q];             \
      }                                                                       \
    }                                                                         \
    _Pragma("unroll") for (int jt = 0; jt < 8; ++jt) {                        \
      f16x4 hn;                                                               \
      _Pragma("unroll") for (int q = 0; q < 4; ++q)                           \
        hn[q] = (_Float16)fast_tanh(ac[jt][q]);                               \
      *(f16x4*)&planes[(CUR) ^ 1][m][16 * jt + 4 * g] = hn;                   \
    }                                                                         \
  }

template <int DEC>
__device__ __forceinline__ void rnn_phase(
    const float* __restrict__ xin, float* __restrict__ out,
    _Float16 (&planes)[2][ROWS][PSTR],
    const f16x8 (&Aw)[8][4], const f16x8 (&AX)[8],
    const f16x8 (&Afc)[2][4], const float (&fcbv)[2][4],
    int b0, int m, int g)
{
    const float* xrow  = xin + ((long)(b0 + m) * TT) * NI + 8 * g;
    float*       fcout = out + (long)(b0 + m) * TT * NC + 4 * g;
    const f32x4 zc = {0.f, 0.f, 0.f, 0.f};

    float4 xa0, xa1, xb0, xb1;
    load_xe(xrow + 0 * NI, g, xa0, xa1);
    load_xe(xrow + 1 * NI, g, xb0, xb1);

    for (int t = 0; t < TT; t += 2) {
        PHASE_STEP(0, xa0, xa1, t);
        PHASE_STEP(1, xb0, xb1, t + 1);
    }

    if (DEC) {
        // final FC for t = TT-1: state is in planes[0] (TT even)
        f16x8 Bh0 = *(const f16x8*)&planes[0][m][ 0 + 8 * g];
        f16x8 Bh1 = *(const f16x8*)&planes[0][m][32 + 8 * g];
        f16x8 Bh2 = *(const f16x8*)&planes[0][m][64 + 8 * g];
        f16x8 Bh3 = *(const f16x8*)&planes[0][m][96 + 8 * g];
        f32x4 f0 = zc, f1 = zc;
        f0 = MFMA16(Afc[0][0], Bh0, f0);  f1 = MFMA16(Afc[1][0], Bh0, f1);
        f0 = MFMA16(Afc[0][1], Bh1, f0);  f1 = MFMA16(Afc[1][1], Bh1, f1);
        f0 = MFMA16(Afc[0][2], Bh2, f0);  f1 = MFMA16(Afc[1][2], Bh2, f1);
        f0 = MFMA16(Afc[0][3], Bh3, f0);  f1 = MFMA16(Afc[1][3], Bh3, f1);
        float* op = fcout + (long)(TT - 1) * NC;
#pragma unroll
        for (int q = 0; q < 4; ++q) {
            op[q] = f0[q] + fcbv[0][q];
            if (16 + 4 * g + q < NC) op[16 + q] = f1[q] + fcbv[1][q];
        }
    }
}

// One wave (64 threads) per block owns 16 batch rows end-to-end:
// encoder 256 steps, then decoder 256 steps with fused FC. No barriers.
__launch_bounds__(64, 1)
__global__ void seq2seq_fused(const float* __restrict__ enc_in,
                              const float* __restrict__ h0p,   // [1,B,H]
                              const float* __restrict__ dec_in,
                              const float* __restrict__ eWih,
                              const float* __restrict__ eWhh,
                              const float* __restrict__ ebih,
                              const float* __restrict__ ebhh,
                              const float* __restrict__ dWih,
                              const float* __restrict__ dWhh,
                              const float* __restrict__ dbih,
                              const float* __restrict__ dbhh,
                              const float* __restrict__ fcW,
                              const float* __restrict__ fcb,
                              float* __restrict__ out)
{
    __shared__ __align__(16) _Float16 planes[2][ROWS][PSTR];

    const int lane = threadIdx.x & 63;
    const int m    = lane & 15;
    const int g    = lane >> 4;
    const int b0   = blockIdx.x * ROWS;

    // h0 -> planes[0]: lane (g,m) writes row m, cols [32g, 32g+32)
#pragma unroll
    for (int u = 0; u < 4; ++u) {
        const float* hp = h0p + (long)(b0 + m) * HH + 32 * g + 8 * u;
        float4 v0 = *(const float4*)hp;
        float4 v1 = *(const float4*)(hp + 4);
        *(f16x8*)&planes[0][m][32 * g + 8 * u] = cvt8(v0, v1);
    }

    f16x8 Aw[8][4], AX[8], Afc[2][4];
    float fcbv[2][4] = {};

    load_rnn_weights(eWih, eWhh, ebih, ebhh, m, g, Aw, AX);
    rnn_phase<0>(enc_in, out, planes, Aw, AX, Afc, fcbv, b0, m, g);

    load_rnn_weights(dWih, dWhh, dbih, dbhh, m, g, Aw, AX);
    load_fc(fcW, fcb, m, g, Afc, fcbv);
    rnn_phase<1>(dec_in, out, planes, Aw, AX, Afc, fcbv, b0, m, g);
}

extern "C" void kernel_launch(void* const* d_in, const int* in_sizes, int n_in,
                              void* d_out, int out_size, void* d_ws, size_t ws_size,
                              hipStream_t stream) {
    const float* enc_in  = (const float*)d_in[0];
    const float* enc_h0  = (const float*)d_in[1];
    const float* dec_in  = (const float*)d_in[2];
    const float* enc_Wih = (const float*)d_in[3];
    const float* enc_Whh = (const float*)d_in[4];
    const float* enc_bih = (const float*)d_in[5];
    const float* enc_bhh = (const float*)d_in[6];
    const float* dec_Wih = (const float*)d_in[7];
    const float* dec_Whh = (const float*)d_in[8];
    const float* dec_bih = (const float*)d_in[9];
    const float* dec_bhh = (const float*)d_in[10];
    const float* fc_W    = (const float*)d_in[11];
    const float* fc_b    = (const float*)d_in[12];
    float* out = (float*)d_out;

    dim3 grid(2048 / ROWS), block(64);
    seq2seq_fused<<<grid, block, 0, stream>>>(enc_in, enc_h0, dec_in,
                                              enc_Wih, enc_Whh, enc_bih, enc_bhh,
                                              dec_Wih, dec_Whh, dec_bih, dec_bhh,
                                              fc_W, fc_b, out);
}

// Round 7
// 481.148 us; speedup vs baseline: 1.3037x; 1.3037x over previous
//
#include <hip/hip_runtime.h>
#include <math.h>

#define TT 256
#define NI 29
#define HH 128
#define NC 29
#define ROWS 16
#define PSTR 136   // fp16 plane stride (halfs); rows 272 B

typedef _Float16 f16x8 __attribute__((ext_vector_type(8)));
typedef _Float16 f16x4 __attribute__((ext_vector_type(4)));
typedef float f32x4 __attribute__((ext_vector_type(4)));

// tanh(x) = 1 - 2/(e^{2x}+1); e^{2x} = 2^{2x*log2(e)}. Graceful at +-inf.
__device__ __forceinline__ float fast_tanh(float x) {
    float e = __builtin_amdgcn_exp2f(x * 2.885390081777927f);
    return 1.0f - 2.0f * __builtin_amdgcn_rcpf(e + 1.0f);
}

__device__ __forceinline__ f16x8 cvt8(const float4& a, const float4& b) {
    f16x8 r;
    r[0] = (_Float16)a.x; r[1] = (_Float16)a.y;
    r[2] = (_Float16)a.z; r[3] = (_Float16)a.w;
    r[4] = (_Float16)b.x; r[5] = (_Float16)b.y;
    r[6] = (_Float16)b.z; r[7] = (_Float16)b.w;
    return r;
}

// per-lane chunk of x~ = [x(29), 1(bias col), 0, 0]: i = 8g..8g+7
__device__ __forceinline__ void load_xe(const float* p, int g, float4& a, float4& b) {
    a = *(const float4*)p;
    if (g < 3) {
        b = *(const float4*)(p + 4);
    } else {
        b.x = p[4];            // i = 28
        b.y = 1.0f;            // i = 29: constant-1 -> bias column
        b.z = 0.f; b.w = 0.f;
    }
}

#define MFMA16(A, B, C) __builtin_amdgcn_mfma_f32_16x16x32_f16((A), (B), (C), 0, 0, 0)

// W~ih[j][k]: k<29 -> Wih, k=29 -> bih+bhh, else 0. Wave w owns j in [64w,64w+64).
__device__ __forceinline__ void load_rnn_weights(
    const float* __restrict__ Wih, const float* __restrict__ Whh,
    const float* __restrict__ bih, const float* __restrict__ bhh,
    int w, int m, int g, f16x8 (&Aw)[4][4], f16x8 (&AX)[4])
{
#pragma unroll
    for (int u = 0; u < 4; ++u) {
        const int j = 16 * (4 * w + u) + m;
#pragma unroll
        for (int s = 0; s < 4; ++s) {
            const float* p = Whh + j * HH + 32 * s + 8 * g;
            float4 v0 = *(const float4*)p;
            float4 v1 = *(const float4*)(p + 4);
            Aw[u][s] = cvt8(v0, v1);
        }
        f16x8 a;
#pragma unroll
        for (int e = 0; e < 8; ++e) {
            int k = 8 * g + e;
            float v = (k < NI) ? Wih[j * NI + k]
                               : (k == NI ? bih[j] + bhh[j] : 0.f);
            a[e] = (_Float16)v;
        }
        AX[u] = a;
    }
}

// FC: wave w handles c-tile w (c = 16w..16w+15, masked at 29)
__device__ __forceinline__ void load_fc(
    const float* __restrict__ fcW, const float* __restrict__ fcb,
    int w, int m, int g, f16x8 (&Afc)[4], float (&fcbv)[4])
{
    const int c = 16 * w + m;
#pragma unroll
    for (int s = 0; s < 4; ++s) {
        f16x8 a;
#pragma unroll
        for (int e = 0; e < 8; ++e) {
            int k = 32 * s + 8 * g + e;
            a[e] = (c < NC) ? (_Float16)fcW[c * HH + k] : (_Float16)0.f;
        }
        Afc[s] = a;
    }
#pragma unroll
    for (int q = 0; q < 4; ++q) {
        int c2 = 16 * w + 4 * g + q;
        fcbv[q] = (c2 < NC) ? fcb[c2] : 0.f;
    }
}

// One step. MFMA 16x16x32 layouts (m89/m91; confirmed end-to-end R2/R4/R5):
//   A[m][k]: m=lane&15, k=(lane>>4)*8+e ; B[k][n]: n=lane&15, same k
//   C/D: col=lane&15 (batch), row=(lane>>4)*4+reg (j within tile)
// Reads planes[CUR] (full h), writes own j-half to planes[CUR^1].
// Raw s_barrier + lgkmcnt(0): no vmcnt drain (x prefetch + FC stores in flight).
#define STEP(CUR, XF0, XF1, TV)                                               \
  {                                                                           \
    f16x8 Bh0 = *(const f16x8*)&planes[CUR][m][ 0 + 8 * g];                   \
    f16x8 Bh1 = *(const f16x8*)&planes[CUR][m][32 + 8 * g];                   \
    f16x8 Bh2 = *(const f16x8*)&planes[CUR][m][64 + 8 * g];                   \
    f16x8 Bh3 = *(const f16x8*)&planes[CUR][m][96 + 8 * g];                   \
    f16x8 BX = cvt8(XF0, XF1);                                                \
    if ((TV) + 2 < TT) load_xe(xrow + ((TV) + 2) * NI, g, XF0, XF1);          \
    f32x4 a0 = MFMA16(AX[0], BX, zc);                                         \
    f32x4 a1 = MFMA16(AX[1], BX, zc);                                         \
    f32x4 a2 = MFMA16(AX[2], BX, zc);                                         \
    f32x4 a3 = MFMA16(AX[3], BX, zc);                                         \
    a0 = MFMA16(Aw[0][0], Bh0, a0);  a1 = MFMA16(Aw[1][0], Bh0, a1);          \
    a2 = MFMA16(Aw[2][0], Bh0, a2);  a3 = MFMA16(Aw[3][0], Bh0, a3);          \
    a0 = MFMA16(Aw[0][1], Bh1, a0);  a1 = MFMA16(Aw[1][1], Bh1, a1);          \
    a2 = MFMA16(Aw[2][1], Bh1, a2);  a3 = MFMA16(Aw[3][1], Bh1, a3);          \
    a0 = MFMA16(Aw[0][2], Bh2, a0);  a1 = MFMA16(Aw[1][2], Bh2, a1);          \
    a2 = MFMA16(Aw[2][2], Bh2, a2);  a3 = MFMA16(Aw[3][2], Bh2, a3);          \
    a0 = MFMA16(Aw[0][3], Bh3, a0);  a1 = MFMA16(Aw[1][3], Bh3, a1);          \
    a2 = MFMA16(Aw[2][3], Bh3, a2);  a3 = MFMA16(Aw[3][3], Bh3, a3);          \
    if (DEC && (TV) > 0) {                                                    \
      f32x4 f0 = MFMA16(Afc[0], Bh0, zc);                                     \
      f32x4 f1 = MFMA16(Afc[1], Bh1, zc);                                     \
      f0 = MFMA16(Afc[2], Bh2, f0);                                           \
      f1 = MFMA16(Afc[3], Bh3, f1);                                           \
      float* op = fcout + (long)((TV) - 1) * NC;                              \
      _Pragma("unroll") for (int q = 0; q < 4; ++q)                           \
        if (cb + q < NC) op[q] = f0[q] + f1[q] + fcbv[q];                     \
    }                                                                         \
    {                                                                         \
      f16x4 h0, h1, h2, h3;                                                   \
      _Pragma("unroll") for (int q = 0; q < 4; ++q) {                         \
        h0[q] = (_Float16)fast_tanh(a0[q]);                                   \
        h1[q] = (_Float16)fast_tanh(a1[q]);                                   \
        h2[q] = (_Float16)fast_tanh(a2[q]);                                   \
        h3[q] = (_Float16)fast_tanh(a3[q]);                                   \
      }                                                                       \
      *(f16x4*)&planes[(CUR) ^ 1][m][16 * (4 * w + 0) + 4 * g] = h0;          \
      *(f16x4*)&planes[(CUR) ^ 1][m][16 * (4 * w + 1) + 4 * g] = h1;          \
      *(f16x4*)&planes[(CUR) ^ 1][m][16 * (4 * w + 2) + 4 * g] = h2;          \
      *(f16x4*)&planes[(CUR) ^ 1][m][16 * (4 * w + 3) + 4 * g] = h3;          \
    }                                                                         \
    asm volatile("s_waitcnt lgkmcnt(0)" ::: "memory");                        \
    __builtin_amdgcn_s_barrier();                                             \
    __builtin_amdgcn_sched_barrier(0);                                        \
  }

template <int DEC>
__device__ __forceinline__ void rnn_phase(
    const float* __restrict__ xin, float* __restrict__ out,
    _Float16 (&planes)[2][ROWS][PSTR],
    const f16x8 (&Aw)[4][4], const f16x8 (&AX)[4],
    const f16x8 (&Afc)[4], const float (&fcbv)[4],
    int b0, int w, int m, int g)
{
    const float* xrow = xin + ((long)(b0 + m) * TT) * NI + 8 * g;
    const int    cb   = 16 * w + 4 * g;
    float*      fcout = out + (long)(b0 + m) * TT * NC + cb;
    const f32x4 zc = {0.f, 0.f, 0.f, 0.f};

    float4 xa0, xa1, xb0, xb1;
    load_xe(xrow + 0 * NI, g, xa0, xa1);
    load_xe(xrow + 1 * NI, g, xb0, xb1);

    for (int t = 0; t < TT; t += 2) {
        STEP(0, xa0, xa1, t);
        STEP(1, xb0, xb1, t + 1);
    }

    if (DEC) {
        // final FC for t = TT-1: h_T is in planes[0] (TT even)
        f16x8 Bh0 = *(const f16x8*)&planes[0][m][ 0 + 8 * g];
        f16x8 Bh1 = *(const f16x8*)&planes[0][m][32 + 8 * g];
        f16x8 Bh2 = *(const f16x8*)&planes[0][m][64 + 8 * g];
        f16x8 Bh3 = *(const f16x8*)&planes[0][m][96 + 8 * g];
        f32x4 f0 = MFMA16(Afc[0], Bh0, zc);
        f32x4 f1 = MFMA16(Afc[1], Bh1, zc);
        f0 = MFMA16(Afc[2], Bh2, f0);
        f1 = MFMA16(Afc[3], Bh3, f1);
        float* op = fcout + (long)(TT - 1) * NC;
#pragma unroll
        for (int q = 0; q < 4; ++q)
            if (cb + q < NC) op[q] = f0[q] + f1[q] + fcbv[q];
    }
}

// 128 blocks x 128 threads (2 waves). Wave w owns j in [64w, 64w+64) for 16
// batch rows; h exchanged via LDS double-buffer with one 2-wave barrier/step.
// Encoder then decoder fused: h_T handoff stays in LDS. FC fused in decoder.
__launch_bounds__(128, 1)
__global__ void seq2seq_fused(const float* __restrict__ enc_in,
                              const float* __restrict__ h0p,   // [1,B,H]
                              const float* __restrict__ dec_in,
                              const float* __restrict__ eWih,
                              const float* __restrict__ eWhh,
                              const float* __restrict__ ebih,
                              const float* __restrict__ ebhh,
                              const float* __restrict__ dWih,
                              const float* __restrict__ dWhh,
                              const float* __restrict__ dbih,
                              const float* __restrict__ dbhh,
                              const float* __restrict__ fcW,
                              const float* __restrict__ fcb,
                              float* __restrict__ out)
{
    __shared__ __align__(16) _Float16 planes[2][ROWS][PSTR];

    const int tid  = threadIdx.x;
    const int w    = tid >> 6;          // wave 0/1
    const int lane = tid & 63;
    const int m    = lane & 15;
    const int g    = lane >> 4;
    const int b0   = blockIdx.x * ROWS;

    // h0 -> planes[0]: 128 threads x 16 halfs
    {
        int b  = tid >> 3;              // 0..15
        int i0 = (tid & 7) * 16;        // 0..112
        const float* hp = h0p + (long)(b0 + b) * HH + i0;
        float4 v0 = *(const float4*)(hp + 0);
        float4 v1 = *(const float4*)(hp + 4);
        float4 v2 = *(const float4*)(hp + 8);
        float4 v3 = *(const float4*)(hp + 12);
        *(f16x8*)&planes[0][b][i0 + 0] = cvt8(v0, v1);
        *(f16x8*)&planes[0][b][i0 + 8] = cvt8(v2, v3);
    }

    f16x8 Aw[4][4], AX[4], Afc[4];
    float fcbv[4] = {};

    load_rnn_weights(eWih, eWhh, ebih, ebhh, w, m, g, Aw, AX);
    __syncthreads();
    rnn_phase<0>(enc_in, out, planes, Aw, AX, Afc, fcbv, b0, w, m, g);

    // dec weights; safe without barrier: dec step 0 writes planes[1], whose
    // last read was before the enc-final barrier.
    load_rnn_weights(dWih, dWhh, dbih, dbhh, w, m, g, Aw, AX);
    load_fc(fcW, fcb, w, m, g, Afc, fcbv);
    rnn_phase<1>(dec_in, out, planes, Aw, AX, Afc, fcbv, b0, w, m, g);
}

extern "C" void kernel_launch(void* const* d_in, const int* in_sizes, int n_in,
                              void* d_out, int out_size, void* d_ws, size_t ws_size,
                              hipStream_t stream) {
    const float* enc_in  = (const float*)d_in[0];
    const float* enc_h0  = (const float*)d_in[1];
    const float* dec_in  = (const float*)d_in[2];
    const float* enc_Wih = (const float*)d_in[3];
    const float* enc_Whh = (const float*)d_in[4];
    const float* enc_bih = (const float*)d_in[5];
    const float* enc_bhh = (const float*)d_in[6];
    const float* dec_Wih = (const float*)d_in[7];
    const float* dec_Whh = (const float*)d_in[8];
    const float* dec_bih = (const float*)d_in[9];
    const float* dec_bhh = (const float*)d_in[10];
    const float* fc_W    = (const float*)d_in[11];
    const float* fc_b    = (const float*)d_in[12];
    float* out = (float*)d_out;

    dim3 grid(2048 / ROWS), block(128);
    seq2seq_fused<<<grid, block, 0, stream>>>(enc_in, enc_h0, dec_in,
                                              enc_Wih, enc_Whh, enc_bih, enc_bhh,
                                              dec_Wih, dec_Whh, dec_bih, dec_bhh,
                                              fc_W, fc_b, out);
}